// Round 1
// baseline (16417.134 us; speedup 1.0000x reference)
//
#include <hip/hip_runtime.h>

#define S_LEN 256
#define B_SZ  256
#define N_MEM 128
#define D_DIM 256
#define C_DIM 512

typedef __bf16 bf16x8 __attribute__((ext_vector_type(8)));
typedef unsigned short ushort8 __attribute__((ext_vector_type(8)));
typedef float floatx4 __attribute__((ext_vector_type(4)));

__device__ __forceinline__ unsigned short f2bf(float f){
  unsigned u = __float_as_uint(f);
  u += 0x7FFFu + ((u >> 16) & 1u);
  return (unsigned short)(u >> 16);
}
__device__ __forceinline__ float sigm(float x){ return 1.f/(1.f + __expf(-x)); }

__device__ __forceinline__ floatx4 mfma16(bf16x8 a, bf16x8 b, floatx4 c){
  return __builtin_amdgcn_mfma_f32_16x16x32_bf16(a, b, c, 0, 0, 0);
}

// ---------------- prologue kernels (run once per call) ----------------

// Wg[n][k] = bf16( k<256 ? W_ih[n][k] : W_hh[n][k-256] )   (2048 x 768)
__global__ __launch_bounds__(256) void p1_wg(const float* __restrict__ Wih,
                                             const float* __restrict__ Whh,
                                             unsigned short* __restrict__ Wg){
  int idx = blockIdx.x*256 + threadIdx.x;            // 2048*768
  int n = idx / 768, k = idx - n*768;
  float v = (k < 256) ? Wih[n*256 + k] : Whh[n*512 + (k-256)];
  Wg[idx] = f2bf(v);
}

// T[e][c] = sum_d' Wq[e][d'] * W_read[d'][c]  (256x512);  rq[e] = bq[e] + b_read . Wq[e,:]
__global__ __launch_bounds__(256) void p2_T(const float* __restrict__ Win,
                                            const float* __restrict__ Wread,
                                            const float* __restrict__ bread,
                                            const float* __restrict__ bin,
                                            float* __restrict__ T, float* __restrict__ rq){
  if (blockIdx.x < 512){
    int idx = blockIdx.x*256 + threadIdx.x;
    int e = idx >> 9, cc = idx & 511;
    float acc = 0.f;
    for (int dp = 0; dp < 256; ++dp) acc += Win[e*256 + dp] * Wread[dp*512 + cc];
    T[idx] = acc;
  } else {
    int e = threadIdx.x;
    float acc = bin[e];
    for (int dp = 0; dp < 256; ++dp) acc += bread[dp] * Win[e*256 + dp];
    rq[e] = acc;
  }
}

// W2 (1808 x 512) bf16: rows [0,1024)=GG fold, [1024,1536)=W_write, [1536,1792)=W_erase, 1792=W_rg, 1793=W_wg, pad 0
// bias2[1808]
__global__ __launch_bounds__(256) void p3_w2(const float* __restrict__ Win,
                                             const float* __restrict__ Wwrite,
                                             const float* __restrict__ Werase,
                                             const float* __restrict__ Wrg,
                                             const float* __restrict__ Wwg,
                                             const float* __restrict__ bwrite,
                                             const float* __restrict__ berase,
                                             const float* __restrict__ brg,
                                             const float* __restrict__ bwg,
                                             const float* __restrict__ T,
                                             const float* __restrict__ rq,
                                             unsigned short* __restrict__ W2,
                                             float* __restrict__ bias2){
  int bid = blockIdx.x;
  if (bid < 2048){                                   // GG rows
    int idx = bid*256 + threadIdx.x;
    int j = idx >> 9, cc = idx & 511;
    int h = j >> 8, d = j & 255;
    float acc = 0.f;
    const float* wk = Win + (256 + h*64)*256 + d;    // Wk[e][d], e = h*64+i
    const float* tp = T + (h*64)*512 + cc;
    for (int i = 0; i < 64; ++i) acc += wk[i*256] * tp[i*512];
    W2[(size_t)j*512 + cc] = f2bf(acc);
  } else if (bid < 2048 + 1568){                     // copy rows
    int idx = (bid - 2048)*256 + threadIdx.x;
    int r = idx >> 9, cc = idx & 511;
    float v;
    if      (r < 512) v = Wwrite[r*512 + cc];
    else if (r < 768) v = Werase[(r-512)*512 + cc];
    else if (r == 768) v = Wrg[cc];
    else if (r == 769) v = Wwg[cc];
    else v = 0.f;
    W2[(size_t)(1024 + r)*512 + cc] = f2bf(v);
  } else {                                           // bias2
    int j = (bid - 2048 - 1568)*256 + threadIdx.x;
    if (j >= 1808) return;
    float v;
    if (j < 1024){
      int h = j >> 8, d = j & 255;
      float acc = 0.f;
      for (int i = 0; i < 64; ++i) acc += rq[h*64+i] * Win[(256 + h*64 + i)*256 + d];
      v = acc;
    }
    else if (j < 1536) v = bwrite[j - 1024];
    else if (j < 1792) v = berase[j - 1536];
    else if (j == 1792) v = brg[0];
    else if (j == 1793) v = bwg[0];
    else v = 0.f;
    bias2[j] = v;
  }
}

// Fold[dp][h*256+d] = sum_hd Wv[h*64+hd][d] * W_out[dp][h*64+hd]  (256 x 1024) bf16
// bout2[dp] = b_out[dp] + sum_e W_out[dp][e]*bv[e]
__global__ __launch_bounds__(256) void p4_fold(const float* __restrict__ Win,
                                               const float* __restrict__ Wout,
                                               const float* __restrict__ bout,
                                               const float* __restrict__ bin,
                                               unsigned short* __restrict__ Fold,
                                               float* __restrict__ bout2){
  if (blockIdx.x < 1024){
    int idx = blockIdx.x*256 + threadIdx.x;
    int dp = idx >> 10, j = idx & 1023;
    int h = j >> 8, d = j & 255;
    float acc = 0.f;
    const float* wv = Win + (512 + h*64)*256 + d;
    const float* wo = Wout + dp*256 + h*64;
    for (int i = 0; i < 64; ++i) acc += wv[i*256] * wo[i];
    Fold[(size_t)dp*1024 + j] = f2bf(acc);
  } else {
    int dp = threadIdx.x;
    float acc = bout[dp];
    for (int e = 0; e < 256; ++e) acc += Wout[dp*256 + e] * bin[512 + e];
    bout2[dp] = acc;
  }
}

// mem init (lives in d_out memT region), zero c and h
__global__ __launch_bounds__(256) void p5_init(const float* __restrict__ mem0,
                                               float* __restrict__ mem,
                                               float* __restrict__ c,
                                               unsigned short* __restrict__ hbf){
  int idx = blockIdx.x*256 + threadIdx.x;            // 8388608
  mem[idx] = mem0[idx & 32767];
  if (idx < 131072){ c[idx] = 0.f; hbf[idx] = 0; }
}

// ---------------- per-step kernels ----------------

// gates = [x_t | h] @ Wg^T  (256 x 2048, K=768), bf16 MFMA
__global__ __launch_bounds__(256) void ka_gates(const float* __restrict__ x,
                                                const unsigned short* __restrict__ hbf,
                                                const unsigned short* __restrict__ Wg,
                                                float* __restrict__ gates, int t){
  const int lane = threadIdx.x & 63, wave = threadIdx.x >> 6;
  const int m0 = blockIdx.y*64 + wave*16;
  const int n0 = blockIdx.x*64;
  const int lm = lane & 15, lk = (lane >> 4) * 8;
  const int row = m0 + lm;
  floatx4 acc[4] = {{0,0,0,0},{0,0,0,0},{0,0,0,0},{0,0,0,0}};
  const float* xrow = x + ((size_t)row * S_LEN + t) * D_DIM;
  const unsigned short* hrow = hbf + (size_t)row * C_DIM;
  const unsigned short* wb = Wg + (size_t)(n0 + lm) * 768 + lk;
  #pragma unroll
  for (int kt = 0; kt < 8; ++kt){                    // x segment (k<256), cast f32->bf16
    floatx4 f0 = *(const floatx4*)(xrow + kt*32 + lk);
    floatx4 f1 = *(const floatx4*)(xrow + kt*32 + lk + 4);
    ushort8 u;
    u[0]=f2bf(f0[0]); u[1]=f2bf(f0[1]); u[2]=f2bf(f0[2]); u[3]=f2bf(f0[3]);
    u[4]=f2bf(f1[0]); u[5]=f2bf(f1[1]); u[6]=f2bf(f1[2]); u[7]=f2bf(f1[3]);
    bf16x8 a = __builtin_bit_cast(bf16x8, u);
    #pragma unroll
    for (int nf = 0; nf < 4; ++nf)
      acc[nf] = mfma16(a, *(const bf16x8*)(wb + (size_t)nf*16*768 + kt*32), acc[nf]);
  }
  #pragma unroll
  for (int kt = 8; kt < 24; ++kt){                   // h segment
    bf16x8 a = *(const bf16x8*)(hrow + kt*32 + lk - 256);
    #pragma unroll
    for (int nf = 0; nf < 4; ++nf)
      acc[nf] = mfma16(a, *(const bf16x8*)(wb + (size_t)nf*16*768 + kt*32), acc[nf]);
  }
  const int r0 = m0 + ((lane >> 4) << 2);
  #pragma unroll
  for (int nf = 0; nf < 4; ++nf){
    int cc = n0 + nf*16 + lm;
    #pragma unroll
    for (int r = 0; r < 4; ++r)
      gates[(size_t)(r0 + r) * 2048 + cc] = acc[nf][r];
  }
}

// blocks [0,512): LSTM elementwise -> c (f32), h (bf16)
// blocks [512,528): read_out GEMM for step t-1 + output write
__global__ __launch_bounds__(256) void klo(const float* __restrict__ gates,
                                           const float* __restrict__ bih,
                                           const float* __restrict__ bhh,
                                           float* __restrict__ c,
                                           unsigned short* __restrict__ hbf,
                                           const unsigned short* __restrict__ mctx,
                                           const unsigned short* __restrict__ Fold,
                                           const float* __restrict__ proj,
                                           const float* __restrict__ bout2,
                                           const float* __restrict__ x,
                                           float* __restrict__ out, int t){
  if (blockIdx.x < 512){
    if (t >= S_LEN) return;
    const int idx = blockIdx.x*256 + threadIdx.x;    // b*512+u
    const int b = idx >> 9, u = idx & 511;
    const float* g = gates + (size_t)b * 2048;
    const float gi = g[u]        + bih[u]        + bhh[u];
    const float gf = g[512 + u]  + bih[512 + u]  + bhh[512 + u];
    const float gg = g[1024 + u] + bih[1024 + u] + bhh[1024 + u];
    const float go = g[1536 + u] + bih[1536 + u] + bhh[1536 + u];
    const float cn = sigm(gf) * c[idx] + sigm(gi) * tanhf(gg);
    c[idx] = cn;
    hbf[idx] = f2bf(sigm(go) * tanhf(cn));
  } else {
    if (t < 1) return;
    const int lane = threadIdx.x & 63, wave = threadIdx.x >> 6;
    const int wv = (blockIdx.x - 512)*4 + wave;      // 0..63
    const int rt = wv & 15, cg = wv >> 4;
    const int lm = lane & 15, lk = (lane >> 4) * 8;
    const int m0 = rt*16, n0 = cg*64;
    const unsigned short* ap = mctx + (size_t)(m0 + lm)*1024 + lk;
    const unsigned short* bp = Fold + (size_t)(n0 + lm)*1024 + lk;
    floatx4 acc[4] = {{0,0,0,0},{0,0,0,0},{0,0,0,0},{0,0,0,0}};
    #pragma unroll
    for (int kt = 0; kt < 32; ++kt){
      bf16x8 a = *(const bf16x8*)(ap + kt*32);
      #pragma unroll
      for (int nf = 0; nf < 4; ++nf)
        acc[nf] = mfma16(a, *(const bf16x8*)(bp + (size_t)nf*16*1024 + kt*32), acc[nf]);
    }
    const int r0 = m0 + ((lane >> 4) << 2);
    #pragma unroll
    for (int nf = 0; nf < 4; ++nf){
      const int dp = n0 + nf*16 + lm;
      const float bo = bout2[dp];
      #pragma unroll
      for (int r = 0; r < 4; ++r){
        const int bb = r0 + r;
        const float rg = proj[(size_t)bb*1808 + 1792];
        const size_t oi = ((size_t)bb * S_LEN + (t-1)) * D_DIM + dp;
        out[oi] = x[oi] + rg * (acc[nf][r] + bo);
      }
    }
  }
}

// proj = h @ W2^T + bias2 (256 x 1808, K=512); sigmoid on cols [1536,1794)
__global__ __launch_bounds__(256) void kb_proj(const unsigned short* __restrict__ hbf,
                                               const unsigned short* __restrict__ W2,
                                               const float* __restrict__ bias2,
                                               float* __restrict__ proj){
  const int lane = threadIdx.x & 63, wave = threadIdx.x >> 6;
  const int tile = blockIdx.x*4 + wave;              // 0..1807
  const int rt = tile & 15, ct = tile >> 4;
  const int lm = lane & 15, lk = (lane >> 4) * 8;
  const unsigned short* ap = hbf + (size_t)(rt*16 + lm)*512 + lk;
  const unsigned short* bp = W2 + (size_t)(ct*16 + lm)*512 + lk;
  floatx4 acc = {0,0,0,0};
  #pragma unroll
  for (int kt = 0; kt < 16; ++kt)
    acc = mfma16(*(const bf16x8*)(ap + kt*32), *(const bf16x8*)(bp + kt*32), acc);
  const int r0 = rt*16 + ((lane >> 4) << 2);
  const int cc = ct*16 + lm;
  const float bv = bias2[cc];
  const bool sg = (cc >= 1536 && cc < 1794);
  #pragma unroll
  for (int r = 0; r < 4; ++r){
    float v = acc[r] + bv;
    if (sg) v = sigm(v);
    proj[(size_t)(r0 + r)*1808 + cc] = v;
  }
}

// per-b: scores (4 heads + wa) over mem, softmax, mctx accumulate + mem erase/write (in-place)
__global__ __launch_bounds__(256) void kc_attn(const float* __restrict__ proj,
                                               float* __restrict__ mem,
                                               unsigned short* __restrict__ mctx){
  __shared__ float qk4[4][256];
  __shared__ float wk[256], wvs[256], er[256];
  __shared__ float sc[5][256];
  __shared__ float at[5][128];
  const int b = blockIdx.x;
  const int tid = threadIdx.x;
  const float* prow = proj + (size_t)b * 1808;
  for (int i = tid; i < 1024; i += 256) qk4[i >> 8][i & 255] = prow[i];
  wk[tid]  = prow[1024 + tid];
  wvs[tid] = prow[1280 + tid];
  er[tid]  = prow[1536 + tid];
  const float wgv = prow[1793];
  __syncthreads();
  // pass1: dot(mem[n], qk_h) and dot(mem[n], wk); 2 threads per n (d split)
  {
    const int n = tid & 127, half = tid >> 7;
    const float* mr = mem + ((size_t)b * N_MEM + n) * D_DIM + half*128;
    const int db = half * 128;
    float a0=0,a1=0,a2=0,a3=0,a4=0;
    #pragma unroll 4
    for (int i = 0; i < 128; i += 4){
      floatx4 m4 = *(const floatx4*)(mr + i);
      floatx4 q0 = *(const floatx4*)&qk4[0][db+i];
      floatx4 q1 = *(const floatx4*)&qk4[1][db+i];
      floatx4 q2 = *(const floatx4*)&qk4[2][db+i];
      floatx4 q3 = *(const floatx4*)&qk4[3][db+i];
      floatx4 qw = *(const floatx4*)&wk[db+i];
      a0 += m4[0]*q0[0] + m4[1]*q0[1] + m4[2]*q0[2] + m4[3]*q0[3];
      a1 += m4[0]*q1[0] + m4[1]*q1[1] + m4[2]*q1[2] + m4[3]*q1[3];
      a2 += m4[0]*q2[0] + m4[1]*q2[1] + m4[2]*q2[2] + m4[3]*q2[3];
      a3 += m4[0]*q3[0] + m4[1]*q3[1] + m4[2]*q3[2] + m4[3]*q3[3];
      a4 += m4[0]*qw[0] + m4[1]*qw[1] + m4[2]*qw[2] + m4[3]*qw[3];
    }
    sc[0][tid]=a0; sc[1][tid]=a1; sc[2][tid]=a2; sc[3][tid]=a3; sc[4][tid]=a4;
  }
  __syncthreads();
  if (tid < 128){
    #pragma unroll
    for (int j = 0; j < 5; ++j){
      float v = sc[j][tid] + sc[j][tid + 128];
      sc[j][tid] = (j < 4) ? v * 0.125f : v;         // 1/sqrt(64)=0.125 on head scores
    }
  }
  __syncthreads();
  {
    const int w = tid >> 6, l = tid & 63;            // wave w handles row w (+ wave0 does row 4)
    for (int j = w; j < 5; j += 4){
      float v0 = sc[j][l], v1 = sc[j][l + 64];
      float mx = fmaxf(v0, v1);
      #pragma unroll
      for (int off = 32; off; off >>= 1) mx = fmaxf(mx, __shfl_xor(mx, off));
      float e0 = __expf(v0 - mx), e1 = __expf(v1 - mx);
      float sm = e0 + e1;
      #pragma unroll
      for (int off = 32; off; off >>= 1) sm += __shfl_xor(sm, off);
      float inv = 1.f / sm;
      at[j][l] = e0 * inv; at[j][l + 64] = e1 * inv;
    }
  }
  __syncthreads();
  // pass2: mctx[h][d] = sum_n at[h][n]*mem[n][d]; mem update in place
  {
    const int d = tid;
    const float erd = er[d], wvd = wvs[d];
    float m0=0,m1=0,m2=0,m3=0;
    float* mcol = mem + (size_t)b * (N_MEM*D_DIM) + d;
    #pragma unroll 4
    for (int n = 0; n < N_MEM; ++n){
      float m = mcol[(size_t)n * D_DIM];
      float an = at[4][n];
      m0 += at[0][n] * m;
      m1 += at[1][n] * m;
      m2 += at[2][n] * m;
      m3 += at[3][n] * m;
      mcol[(size_t)n * D_DIM] = m * (1.f - an * erd) + wgv * (an * wvd);
    }
    unsigned short* mr = mctx + (size_t)b * 1024;
    mr[d] = f2bf(m0); mr[256+d] = f2bf(m1); mr[512+d] = f2bf(m2); mr[768+d] = f2bf(m3);
  }
}

// ---------------- host ----------------

extern "C" void kernel_launch(void* const* d_in, const int* in_sizes, int n_in,
                              void* d_out, int out_size, void* d_ws, size_t ws_size,
                              hipStream_t stream){
  const float* x      = (const float*)d_in[0];
  const float* mem0   = (const float*)d_in[1];
  const float* Wih    = (const float*)d_in[2];
  const float* Whh    = (const float*)d_in[3];
  const float* bih    = (const float*)d_in[4];
  const float* bhh    = (const float*)d_in[5];
  const float* Wread  = (const float*)d_in[6];
  const float* bread  = (const float*)d_in[7];
  const float* Wwrite = (const float*)d_in[8];
  const float* bwrite = (const float*)d_in[9];
  const float* Werase = (const float*)d_in[10];
  const float* berase = (const float*)d_in[11];
  const float* Win    = (const float*)d_in[12];
  const float* bin    = (const float*)d_in[13];
  const float* Wout   = (const float*)d_in[14];
  const float* bout   = (const float*)d_in[15];
  const float* Wrg    = (const float*)d_in[16];
  const float* brg    = (const float*)d_in[17];
  const float* Wwg    = (const float*)d_in[18];
  const float* bwg    = (const float*)d_in[19];
  float* out = (float*)d_out;
  float* mem = out + (size_t)B_SZ * S_LEN * D_DIM;   // memT region doubles as live memory state

  char* ws = (char*)d_ws;
  size_t off = 0;
  auto alloc = [&](size_t bytes) -> void* {
    void* p = ws + off; off += (bytes + 511) & ~(size_t)511; return p;
  };
  unsigned short* Wg   = (unsigned short*)alloc((size_t)2048*768*2);
  unsigned short* W2   = (unsigned short*)alloc((size_t)1808*512*2);
  unsigned short* Fold = (unsigned short*)alloc((size_t)256*1024*2);
  float* T     = (float*)alloc((size_t)256*512*4);
  float* rq    = (float*)alloc(256*4);
  float* bias2 = (float*)alloc(1808*4);
  float* bout2 = (float*)alloc(256*4);
  float* gates = (float*)alloc((size_t)256*2048*4);
  float* cbuf  = (float*)alloc((size_t)256*512*4);
  unsigned short* hbf  = (unsigned short*)alloc((size_t)256*512*2);
  float* proj  = (float*)alloc((size_t)256*1808*4);
  unsigned short* mctx = (unsigned short*)alloc((size_t)256*1024*2);
  (void)ws_size; (void)in_sizes; (void)n_in; (void)out_size;

  p1_wg  <<<6144, 256, 0, stream>>>(Wih, Whh, Wg);
  p2_T   <<<513,  256, 0, stream>>>(Win, Wread, bread, bin, T, rq);
  p3_w2  <<<3624, 256, 0, stream>>>(Win, Wwrite, Werase, Wrg, Wwg, bwrite, berase, brg, bwg, T, rq, W2, bias2);
  p4_fold<<<1025, 256, 0, stream>>>(Win, Wout, bout, bin, Fold, bout2);
  p5_init<<<32768,256, 0, stream>>>(mem0, mem, cbuf, hbf);

  for (int t = 0; t < S_LEN; ++t){
    ka_gates<<<dim3(32,4), 256, 0, stream>>>(x, hbf, Wg, gates, t);
    klo     <<<528,        256, 0, stream>>>(gates, bih, bhh, cbuf, hbf, mctx, Fold, proj, bout2, x, out, t);
    kb_proj <<<452,        256, 0, stream>>>(hbf, W2, bias2, proj);
    kc_attn <<<256,        256, 0, stream>>>(proj, mem, mctx);
  }
  klo<<<528, 256, 0, stream>>>(gates, bih, bhh, cbuf, hbf, mctx, Fold, proj, bout2, x, out, S_LEN);
}